// Round 6
// baseline (306.955 us; speedup 1.0000x reference)
//
#include <hip/hip_runtime.h>
#include <stdint.h>

// Fused attention: q/k/v projections + softmax(QK^T/32 + mask) @ V
// B=4, S=2048, E=1024.
// GEMM: 256x128 tile, 4 waves (2Mx2N), per-wave 128x64 out (0.44 KB
// LDS-read/MFMA -> MFMA-bound at 2 blocks/CU), BK=32, ring-3 LDS (72KB),
// stage-2-ahead global_load_lds(16B), ONE barrier + vmcnt(6) gate per
// K-tile, verified XOR involution swizzle (0 conflicts), bijective XCD
// swizzle, multi-job fused launches.
//
// ws layout (MB offsets): 0 qb / 16 kb / 32 vT / 48 Sb(32MB) / 80 xq /
// 96 xk / 112 xv / 128 Wqb / 130 Wkb / 132 Wvb   (total 134MB)

typedef __attribute__((ext_vector_type(8))) short s8v;
typedef __attribute__((ext_vector_type(4))) float f32x4;

__device__ __forceinline__ unsigned short f2b(float f) {
  union { float f; unsigned u; } c; c.f = f;
  unsigned r = c.u + 0x7fffu + ((c.u >> 16) & 1u);
  return (unsigned short)(r >> 16);
}
__device__ __forceinline__ float b2f(unsigned short s) {
  union { float f; unsigned u; } c; c.u = ((unsigned)s) << 16; return c.f;
}

__device__ __forceinline__ void gload_lds16(const void* gsrc, void* ldst) {
  __builtin_amdgcn_global_load_lds(
      (__attribute__((address_space(1))) unsigned int*)(uintptr_t)gsrc,
      (__attribute__((address_space(3))) unsigned int*)(unsigned)(uintptr_t)ldst,
      16, 0, 0);
}

struct Job {
  const unsigned short* A; const unsigned short* B; void* C;
  const float* bias; const float* mask;
  long sAb, sBb, sCb, sMb;
  int lda, ldb, ldc, ldM;
  int K, tilesN, tilesMN;
  float scale; int flags;   // bit0: out bf16; bits1-2: bias 0/1(col)/2(row); bit3: mask
};

// NT GEMM: C[m][n] = scale*sum_k A[m][k]B[n][k] (+bias/mask). Tile 256x128.
__global__ __launch_bounds__(256, 2) void gemm_w128(Job j0, Job j1, Job j2,
                                                    int b0, int b1) {
  constexpr int ASZ = 16384;             // A: 256 rows x 64B
  constexpr int SLOT = 24576;            // + B: 128 rows x 64B
  __shared__ __align__(16) char lds[3 * SLOT];

  const int nwg = gridDim.x;
  const int hw = blockIdx.x;
  int g = (hw & 7) * (nwg >> 3) + (hw >> 3);   // bijective XCD swizzle (nwg%8==0)
  const Job J = (g < b0) ? j0 : (g < b1) ? j1 : j2;
  g -= (g < b0) ? 0 : (g < b1) ? b0 : b1;

  const int batch = g / J.tilesMN;
  const int tt = g - batch * J.tilesMN;
  const int tm = tt / J.tilesN, tn = tt - tm * J.tilesN;
  const int brow = tm << 8, bcol = tn << 7;

  const int tid = threadIdx.x, lane = tid & 63, w = tid >> 6;  // 4 waves 2Mx2N
  const int wm = w >> 1, wn = w & 1;
  const int fr = lane & 15, fq = lane >> 4;

  const unsigned short* Ab = J.A + (long)batch * J.sAb;
  const unsigned short* Bb = J.B + (long)batch * J.sBb;
  const int lda = J.lda, ldb = J.ldb;

  // staging: 24 chunks of 1KB per K-tile (A: 0-15, B: 16-23); wave w stages
  // chunks {w, w+4, ..., w+20}. LDS dest linear (wave-uniform + lane*16);
  // global source inverse-swizzled so swizzled ds_reads see logical data.
  const unsigned short* gsrc[6];
  int ldsdst[6];
#pragma unroll
  for (int i = 0; i < 6; i++) {
    const int c = w + i * 4;
    const bool isA = (c < 16);
    const int cc = isA ? c : c - 16;
    const int roff = cc * 1024 + lane * 16;          // region-relative linear
    const int L = roff ^ (((roff >> 7) & 7) << 4);   // involution (verified)
    const int row = L >> 6, colb = L & 63;
    gsrc[i] = (isA ? (Ab + (long)(brow + row) * lda)
                   : (Bb + (long)(bcol + row) * ldb)) + (colb >> 1);
    ldsdst[i] = (isA ? 0 : ASZ) + cc * 1024;
  }

  // ds_read offsets (region-relative, same involution)
  int offA[8], offB[4];
#pragma unroll
  for (int i = 0; i < 8; i++) {
    const int oa = (wm * 128 + i * 16 + fr) * 64 + fq * 16;
    offA[i] = oa ^ (((oa >> 7) & 7) << 4);
  }
#pragma unroll
  for (int i = 0; i < 4; i++) {
    const int ob = (wn * 64 + i * 16 + fr) * 64 + fq * 16;
    offB[i] = ASZ + (ob ^ (((ob >> 7) & 7) << 4));
  }

  f32x4 acc[8][4];
#pragma unroll
  for (int mi = 0; mi < 8; mi++)
#pragma unroll
    for (int ni = 0; ni < 4; ni++) acc[mi][ni] = (f32x4){0.f, 0.f, 0.f, 0.f};

  const int NT = J.K >> 5;

#define STAGE(kt, slot) { \
  char* const sb_ = lds + (slot) * SLOT; \
  _Pragma("unroll") \
  for (int i_ = 0; i_ < 6; i_++) \
    gload_lds16(gsrc[i_] + (long)(kt) * 32, sb_ + ldsdst[i_]); }

  // prologue: stage tiles 0,1; ensure tile 0 resident block-wide
  STAGE(0, 0);
  STAGE(1, 1);
  asm volatile("s_waitcnt vmcnt(6)" ::: "memory");
  __builtin_amdgcn_s_barrier();

  int sRead = 0, sStage = 2;
  for (int t = 0; t < NT; ++t) {
    if (t + 2 < NT) STAGE(t + 2, sStage);   // slot != sRead, != (t+1)'s
    const char* sb = lds + sRead * SLOT;

    s8v af[8], bf[4];
#pragma unroll
    for (int mi = 0; mi < 8; mi++) af[mi] = *(const s8v*)(sb + offA[mi]);
#pragma unroll
    for (int ni = 0; ni < 4; ni++) bf[ni] = *(const s8v*)(sb + offB[ni]);
#pragma unroll
    for (int mi = 0; mi < 8; mi++)
#pragma unroll
      for (int ni = 0; ni < 4; ni++)
        acc[mi][ni] = __builtin_amdgcn_mfma_f32_16x16x32_bf16(
            af[mi], bf[ni], acc[mi][ni], 0, 0, 0);

    if (t + 1 < NT) {
      if (t + 2 < NT) asm volatile("s_waitcnt vmcnt(6)" ::: "memory");
      else            asm volatile("s_waitcnt vmcnt(0)" ::: "memory");
      __builtin_amdgcn_s_barrier();
    }
    sRead  = (sRead  == 2) ? 0 : sRead  + 1;
    sStage = (sStage == 2) ? 0 : sStage + 1;
  }

  // epilogue: C/D frag layout col=lane&15, row=(lane>>4)*4+r  [m89]
  const int obf = J.flags & 1, bmode = (J.flags >> 1) & 3, hasM = (J.flags >> 3) & 1;
  unsigned short* Cb = (unsigned short*)J.C;
  float* Cf = (float*)J.C;
  const long cB = (long)batch * J.sCb;
  const float* maskB = hasM ? (J.mask + (long)batch * J.sMb) : nullptr;
#pragma unroll
  for (int mi = 0; mi < 8; mi++) {
#pragma unroll
    for (int ni = 0; ni < 4; ni++) {
      const int col = bcol + wn * 64 + ni * 16 + fr;
#pragma unroll
      for (int r = 0; r < 4; r++) {
        const int row = brow + wm * 128 + mi * 16 + fq * 4 + r;
        float v = acc[mi][ni][r] * J.scale;
        if (bmode == 1) v += J.bias[col];
        if (bmode == 2) v += J.bias[row];
        if (hasM) v += maskB[(long)row * J.ldM + col];
        if (obf) Cb[cB + (long)row * J.ldc + col] = f2b(v);
        else     Cf[cB + (long)row * J.ldc + col] = v;
      }
    }
  }
#undef STAGE
}

// f32->bf16 for 6 regions in one launch. regions 0-2: n8=1048576, 768 blocks
// each; regions 3-5: n8=131072, 128 blocks each. grid = 2688.
__global__ __launch_bounds__(256) void cvt6(
    const float* s0, unsigned short* d0, const float* s1, unsigned short* d1,
    const float* s2, unsigned short* d2, const float* s3, unsigned short* d3,
    const float* s4, unsigned short* d4, const float* s5, unsigned short* d5) {
  int bid = blockIdx.x;
  const float* src; unsigned short* dst; long n8; int lb, nb;
  if (bid < 2304) {
    int r = bid / 768; lb = bid - r * 768; nb = 768; n8 = 1048576;
    src = r == 0 ? s0 : r == 1 ? s1 : s2;
    dst = r == 0 ? d0 : r == 1 ? d1 : d2;
  } else {
    int r = (bid - 2304) / 128; lb = (bid - 2304) - r * 128; nb = 128; n8 = 131072;
    src = r == 0 ? s3 : r == 1 ? s4 : s5;
    dst = r == 0 ? d3 : r == 1 ? d4 : d5;
  }
  const long stride = (long)nb * 256;
  for (long i = (long)lb * 256 + threadIdx.x; i < n8; i += stride) {
    const float* p = src + i * 8;
    f32x4 va = *(const f32x4*)p;
    f32x4 vb = *(const f32x4*)(p + 4);
    s8v o;
    o[0] = (short)f2b(va[0]); o[1] = (short)f2b(va[1]);
    o[2] = (short)f2b(va[2]); o[3] = (short)f2b(va[3]);
    o[4] = (short)f2b(vb[0]); o[5] = (short)f2b(vb[1]);
    o[6] = (short)f2b(vb[2]); o[7] = (short)f2b(vb[3]);
    *(s8v*)(dst + i * 8) = o;
  }
}

// in-place row softmax over 2048 bf16 entries; one block (4 waves) per row
__global__ __launch_bounds__(256) void softmax_inplace(unsigned short* __restrict__ S) {
  const long row = blockIdx.x;
  unsigned short* rp = S + row * 2048;
  const int tid = threadIdx.x, lane = tid & 63, wid = tid >> 6;

  s8v vb = *(const s8v*)&rp[tid * 8];
  float x[8];
#pragma unroll
  for (int j = 0; j < 8; j++) x[j] = b2f((unsigned short)vb[j]);

  float m = x[0];
#pragma unroll
  for (int j = 1; j < 8; j++) m = fmaxf(m, x[j]);
#pragma unroll
  for (int off = 32; off > 0; off >>= 1) m = fmaxf(m, __shfl_xor(m, off, 64));

  __shared__ float red[4];
  if (lane == 0) red[wid] = m;
  __syncthreads();
  m = fmaxf(fmaxf(red[0], red[1]), fmaxf(red[2], red[3]));
  __syncthreads();

  float s = 0.f;
#pragma unroll
  for (int j = 0; j < 8; j++) { x[j] = __expf(x[j] - m); s += x[j]; }
#pragma unroll
  for (int off = 32; off > 0; off >>= 1) s += __shfl_xor(s, off, 64);
  if (lane == 0) red[wid] = s;
  __syncthreads();
  s = red[0] + red[1] + red[2] + red[3];
  const float inv = 1.0f / s;

  s8v ob;
#pragma unroll
  for (int j = 0; j < 8; j++) ob[j] = (short)f2b(x[j] * inv);
  *(s8v*)&rp[tid * 8] = ob;
}

extern "C" void kernel_launch(void* const* d_in, const int* in_sizes, int n_in,
                              void* d_out, int out_size, void* d_ws, size_t ws_size,
                              hipStream_t stream) {
  const float* q    = (const float*)d_in[0];
  const float* k    = (const float*)d_in[1];
  const float* v    = (const float*)d_in[2];
  const float* mask = (const float*)d_in[3];
  const float* Wq   = (const float*)d_in[4];
  const float* bq   = (const float*)d_in[5];
  const float* Wk   = (const float*)d_in[6];
  const float* bk   = (const float*)d_in[7];
  const float* Wv   = (const float*)d_in[8];
  const float* bv   = (const float*)d_in[9];
  float* out = (float*)d_out;

  const size_t MB = 1ull << 20;
  if (ws_size < 134 * MB) return;
  char* ws = (char*)d_ws;
  unsigned short* qb  = (unsigned short*)(ws + 0 * MB);
  unsigned short* kb  = (unsigned short*)(ws + 16 * MB);
  unsigned short* vT  = (unsigned short*)(ws + 32 * MB);
  unsigned short* Sb  = (unsigned short*)(ws + 48 * MB);
  unsigned short* xq  = (unsigned short*)(ws + 80 * MB);
  unsigned short* xk  = (unsigned short*)(ws + 96 * MB);
  unsigned short* xv  = (unsigned short*)(ws + 112 * MB);
  unsigned short* Wqb = (unsigned short*)(ws + 128 * MB);
  unsigned short* Wkb = (unsigned short*)(ws + 130 * MB);
  unsigned short* Wvb = (unsigned short*)(ws + 132 * MB);

  cvt6<<<2688, 256, 0, stream>>>(q, xq, k, xk, v, xv, Wq, Wqb, Wk, Wkb, Wv, Wvb);

  // QKV fused: q-proj 256 blocks (32x8 tiles), k-proj 256,
  // v-proj 256 (vT: M=1024 -> 4x16 tiles x 4 batches). grid 768.
  Job jq = { xq, Wqb, (void*)qb, bq, nullptr, 0, 0, 0, 0,
             1024, 1024, 1024, 0, 1024, 8, 256, 1.0f, 1 | (1 << 1) };
  Job jk = { xk, Wkb, (void*)kb, bk, nullptr, 0, 0, 0, 0,
             1024, 1024, 1024, 0, 1024, 8, 256, 1.0f, 1 | (1 << 1) };
  Job jv = { Wvb, xv, (void*)vT, bv, nullptr, 0, 2048L * 1024, 1024L * 2048, 0,
             1024, 1024, 2048, 0, 1024, 16, 64, 1.0f, 1 | (2 << 1) };
  gemm_w128<<<768, 256, 0, stream>>>(jq, jk, jv, 256, 512);

  // scores: S = (qb.kb^T)/32 + mask; 8x16 tiles x 4 batches = 512 blocks
  Job js = { qb, kb, (void*)Sb, nullptr, mask,
             2048L * 1024, 2048L * 1024, 2048L * 2048, 2048L * 2048,
             1024, 1024, 2048, 2048, 1024, 16, 128, 0.03125f, 1 | (1 << 3) };
  gemm_w128<<<512, 256, 0, stream>>>(js, js, js, 512, 512);

  softmax_inplace<<<8192, 256, 0, stream>>>(Sb);

  // PV: out = P.vT^T; 8x8 tiles x 4 batches = 256 blocks, K=2048
  Job jp = { Sb, vT, (void*)out, nullptr, nullptr,
             2048L * 2048, 1024L * 2048, 2048L * 1024, 0,
             2048, 2048, 1024, 0, 2048, 8, 64, 1.0f, 0 };
  gemm_w128<<<256, 256, 0, stream>>>(jp, jp, jp, 256, 256);
}

// Round 8
// 225.629 us; speedup vs baseline: 1.3604x; 1.3604x over previous
//
#include <hip/hip_runtime.h>
#include <stdint.h>

// Fused attention: q/k/v projections + softmax(QK^T/32 + mask) @ V
// B=4, S=2048, E=1024.
// GEMM = round-2-measured ring-4 structure: 256xBN tile, 8 waves (2Mx4N),
// BK=32, ring-4 LDS, stage-2-ahead global_load_lds(16B), counted vmcnt(GPW)
// gate + ONE barrier per K-tile, verified XOR involution swizzle (0 bank
// conflicts), setprio clusters, bijective XCD swizzle, 3-job fused launches.
// Softmax eliminated: scores epilogue computes E=exp(x/32+mask) (bounded
// ~e^6), writes E bf16 + atomic row sums; PV epilogue scales by 1/s[row].
//
// ws layout (MB offsets), TIME-MULTIPLEXED (R7 bug: sRow overlapped Wvb):
//   [0,16)   qb      (QKV out)          [48, 48+32KB) sRow  (zeroed by cvt7)
//   [16,32)  kb                          [80,96)  xq  -- dead after QKV -+
//   [32,48)  vT                          [96,112) xk  -- dead after QKV  |
//   [80,112) Sb=E  (scores out; ALIASES xq/xk, written after QKV reads) -+
//   [112,128) xv    [128,130) Wqb  [130,132) Wkb  [132,134) Wvb

typedef __attribute__((ext_vector_type(8))) short s8v;
typedef __attribute__((ext_vector_type(4))) float f32x4;

__device__ __forceinline__ unsigned short f2b(float f) {
  union { float f; unsigned u; } c; c.f = f;
  unsigned r = c.u + 0x7fffu + ((c.u >> 16) & 1u);   // RNE, no NaN inputs
  return (unsigned short)(r >> 16);
}

__device__ __forceinline__ void gload_lds16(const void* gsrc, void* ldst) {
  __builtin_amdgcn_global_load_lds(
      (__attribute__((address_space(1))) unsigned int*)(uintptr_t)gsrc,
      (__attribute__((address_space(3))) unsigned int*)(unsigned)(uintptr_t)ldst,
      16, 0, 0);
}

template <int N> __device__ __forceinline__ void waitvm() {
  if constexpr (N == 4)      asm volatile("s_waitcnt vmcnt(4)" ::: "memory");
  else if constexpr (N == 3) asm volatile("s_waitcnt vmcnt(3)" ::: "memory");
  else                       asm volatile("s_waitcnt vmcnt(0)" ::: "memory");
}

struct Job {
  const unsigned short* A; const unsigned short* B; void* C;
  const float* bias; const float* mask; float* sRow;
  long sAb, sBb, sCb, sMb;
  int lda, ldb, ldc, ldM;
  int K, tilesN, tilesMN;
  float scale; int bmode;    // bias: 0 none, 1 bias[col], 2 bias[row]
};

// NT GEMM: C[m][n] = f(scale*sum_k A[m][k]B[n][k]). M mult of 256, N mult
// of BN=NFRAG*64, K mult of 32. MODE 0: +bias, bf16 out (QKV projections).
// MODE 1: exp(.*scale+mask) -> bf16 out + atomic row sums (scores).
// MODE 2: f32 out * (1/sRow[row]) (PV with normalization).
template <int NFRAG, int MODE>
__global__ __launch_bounds__(512, 2) void gemmJ(Job j0, Job j1, Job j2,
                                                int b0, int b1) {
  constexpr int BN = NFRAG * 64;
  constexpr int ASLOT = 256 * 64;            // bytes: 256 rows x 64B (BK=32)
  constexpr int BSLOT = BN * 64;
  constexpr int SLOT = ASLOT + BSLOT;
  constexpr int CH = SLOT / 1024;            // 1KB chunks per K-tile
  constexpr int GPW = CH / 8;                // gloads per wave per K-tile
  static_assert(4 * SLOT <= 160 * 1024, "LDS budget");
  __shared__ __align__(16) char lds[4 * SLOT];

  const int nwg = gridDim.x;
  const int hw = blockIdx.x;
  int g = (hw & 7) * (nwg >> 3) + (hw >> 3);   // bijective XCD swizzle (nwg%8==0)
  const Job J = (g < b0) ? j0 : (g < b1) ? j1 : j2;
  g -= (g < b0) ? 0 : (g < b1) ? b0 : b1;

  const int batch = g / J.tilesMN;
  const int tt = g - batch * J.tilesMN;
  const int tm = tt / J.tilesN, tn = tt - tm * J.tilesN;
  const int brow = tm << 8, bcol = tn * BN;

  const int tid = threadIdx.x;
  const int lane = tid & 63, w = tid >> 6;     // 8 waves: 2M x 4N
  const int wm = w >> 2, wn = w & 3;
  const int fr = lane & 15, fq = lane >> 4;

  const unsigned short* Ab = J.A + (long)batch * J.sAb;
  const unsigned short* Bb = J.B + (long)batch * J.sBb;

  // staging: CH 1KB chunks (A first, then B); wave w stages {w, w+8, ...}.
  // LDS dest linear (wave-uniform + lane*16); global source inverse-swizzled
  // so swizzled ds_reads see logical data (rule #21; R2-verified, 0 conflicts).
  const unsigned short* gsrc[GPW];
  int ldsdst[GPW];
#pragma unroll
  for (int i = 0; i < GPW; i++) {
    const int c = w + i * 8;
    const bool isA = (c < 16);
    const int cc = isA ? c : c - 16;
    const int roff = cc * 1024 + lane * 16;          // region-relative linear
    const int L = roff ^ (((roff >> 7) & 7) << 4);   // involution
    const int row = L >> 6, colb = L & 63;
    gsrc[i] = (isA ? (Ab + (long)(brow + row) * J.lda)
                   : (Bb + (long)(bcol + row) * J.ldb)) + (colb >> 1);
    ldsdst[i] = (isA ? 0 : ASLOT) + cc * 1024;
  }

  // ds_read offsets (region-relative, same involution)
  int offA[8], offB[NFRAG];
#pragma unroll
  for (int mi = 0; mi < 8; mi++) {
    const int oa = (wm * 128 + mi * 16 + fr) * 64 + fq * 16;
    offA[mi] = oa ^ (((oa >> 7) & 7) << 4);
  }
#pragma unroll
  for (int ni = 0; ni < NFRAG; ni++) {
    const int ob = (wn * (NFRAG * 16) + ni * 16 + fr) * 64 + fq * 16;
    offB[ni] = ASLOT + (ob ^ (((ob >> 7) & 7) << 4));
  }

  f32x4 acc[8][NFRAG];
#pragma unroll
  for (int mi = 0; mi < 8; mi++)
#pragma unroll
    for (int ni = 0; ni < NFRAG; ni++) acc[mi][ni] = (f32x4){0.f, 0.f, 0.f, 0.f};

  const int NT = J.K >> 5;

#define STAGE(kt) { \
  char* const sb_ = lds + ((kt) & 3) * SLOT; \
  _Pragma("unroll") \
  for (int i_ = 0; i_ < GPW; i_++) \
    gload_lds16(gsrc[i_] + (long)(kt) * 32, sb_ + ldsdst[i_]); }

  // prologue: stage tiles 0,1; tile 0 resident block-wide
  STAGE(0);
  STAGE(1);
  waitvm<GPW>();
  __builtin_amdgcn_s_barrier();

  for (int t = 0; t < NT; ++t) {
    const char* sb = lds + (t & 3) * SLOT;
    if (t + 2 < NT) STAGE(t + 2);            // slot (t+2)&3 != t&3, (t+1)&3

    s8v bf[NFRAG], af[4];
#pragma unroll
    for (int ni = 0; ni < NFRAG; ni++) bf[ni] = *(const s8v*)(sb + offB[ni]);
#pragma unroll
    for (int mi = 0; mi < 4; mi++) af[mi] = *(const s8v*)(sb + offA[mi]);
    __builtin_amdgcn_s_setprio(1);
#pragma unroll
    for (int mi = 0; mi < 4; mi++)
#pragma unroll
      for (int ni = 0; ni < NFRAG; ni++)
        acc[mi][ni] = __builtin_amdgcn_mfma_f32_16x16x32_bf16(
            af[mi], bf[ni], acc[mi][ni], 0, 0, 0);
    __builtin_amdgcn_s_setprio(0);
#pragma unroll
    for (int mi = 0; mi < 4; mi++) af[mi] = *(const s8v*)(sb + offA[4 + mi]);
    __builtin_amdgcn_s_setprio(1);
#pragma unroll
    for (int mi = 0; mi < 4; mi++)
#pragma unroll
      for (int ni = 0; ni < NFRAG; ni++)
        acc[4 + mi][ni] = __builtin_amdgcn_mfma_f32_16x16x32_bf16(
            af[mi], bf[ni], acc[4 + mi][ni], 0, 0, 0);
    __builtin_amdgcn_s_setprio(0);

    if (t + 1 < NT) {
      if (t + 2 < NT) waitvm<GPW>();          // counted: tile t+1 resident
      else            waitvm<0>();            // tail drain
      __builtin_amdgcn_s_barrier();
    }
  }

  // epilogue: C/D frag layout col=lane&15, row=(lane>>4)*4+r  [m89]
  unsigned short* Cb = (unsigned short*)J.C;
  float* Cf = (float*)J.C;
  const long cB = (long)batch * J.sCb;
  const float* maskB = (MODE == 1) ? (J.mask + (long)batch * J.sMb) : nullptr;
  float* sB = (MODE != 0) ? (J.sRow + batch * 2048) : nullptr;

#pragma unroll
  for (int mi = 0; mi < 8; mi++) {
    const int rbase = brow + wm * 128 + mi * 16 + fq * 4;

    if constexpr (MODE == 0) {
#pragma unroll
      for (int ni = 0; ni < NFRAG; ni++) {
        const int col = bcol + wn * (NFRAG * 16) + ni * 16 + fr;
        const float bc = (J.bmode == 1) ? J.bias[col] : 0.f;
#pragma unroll
        for (int r = 0; r < 4; r++) {
          const int row = rbase + r;
          float v = acc[mi][ni][r] + ((J.bmode == 2) ? J.bias[row] : bc);
          Cb[cB + (long)row * J.ldc + col] = f2b(v);
        }
      }
    } else if constexpr (MODE == 1) {
      float rs[4] = {0.f, 0.f, 0.f, 0.f};
#pragma unroll
      for (int ni = 0; ni < NFRAG; ni++) {
        const int col = bcol + wn * (NFRAG * 16) + ni * 16 + fr;
#pragma unroll
        for (int r = 0; r < 4; r++) {
          const int row = rbase + r;
          float v = acc[mi][ni][r] * J.scale + maskB[(long)row * J.ldM + col];
          v = __expf(v);                       // bounded: scores ~N(0,1)
          Cb[cB + (long)row * J.ldc + col] = f2b(v);
          rs[r] += v;
        }
      }
#pragma unroll
      for (int off = 1; off < 16; off <<= 1) {
#pragma unroll
        for (int r = 0; r < 4; r++) rs[r] += __shfl_xor(rs[r], off, 64);
      }
      if (fr == 0) {
#pragma unroll
        for (int r = 0; r < 4; r++) atomicAdd(&sB[rbase + r], rs[r]);
      }
    } else {  // MODE 2: PV normalize
      float inv[4];
#pragma unroll
      for (int r = 0; r < 4; r++) inv[r] = 1.0f / sB[rbase + r];
#pragma unroll
      for (int ni = 0; ni < NFRAG; ni++) {
        const int col = bcol + wn * (NFRAG * 16) + ni * 16 + fr;
#pragma unroll
        for (int r = 0; r < 4; r++) {
          const int row = rbase + r;
          Cf[cB + (long)row * J.ldc + col] = acc[mi][ni][r] * inv[r];
        }
      }
    }
  }
#undef STAGE
}

// f32->bf16 for 6 regions + zero sRow. regions 0-2: n8=1048576, 768 blocks
// each; 3-5: n8=131072, 128 blocks each; blocks 2688-2695 zero sRow[8192].
__global__ __launch_bounds__(256) void cvt7(
    const float* s0, unsigned short* d0, const float* s1, unsigned short* d1,
    const float* s2, unsigned short* d2, const float* s3, unsigned short* d3,
    const float* s4, unsigned short* d4, const float* s5, unsigned short* d5,
    float* sz) {
  int bid = blockIdx.x;
  if (bid >= 2688) {
    for (int i = (bid - 2688) * 256 + threadIdx.x; i < 8192; i += 2048)
      sz[i] = 0.f;
    return;
  }
  const float* src; unsigned short* dst; long n8; int lb, nb;
  if (bid < 2304) {
    int r = bid / 768; lb = bid - r * 768; nb = 768; n8 = 1048576;
    src = r == 0 ? s0 : r == 1 ? s1 : s2;
    dst = r == 0 ? d0 : r == 1 ? d1 : d2;
  } else {
    int r = (bid - 2304) / 128; lb = (bid - 2304) - r * 128; nb = 128; n8 = 131072;
    src = r == 0 ? s3 : r == 1 ? s4 : s5;
    dst = r == 0 ? d3 : r == 1 ? d4 : d5;
  }
  const long stride = (long)nb * 256;
  for (long i = (long)lb * 256 + threadIdx.x; i < n8; i += stride) {
    const float* p = src + i * 8;
    f32x4 va = *(const f32x4*)p;
    f32x4 vb = *(const f32x4*)(p + 4);
    s8v o;
    o[0] = (short)f2b(va[0]); o[1] = (short)f2b(va[1]);
    o[2] = (short)f2b(va[2]); o[3] = (short)f2b(va[3]);
    o[4] = (short)f2b(vb[0]); o[5] = (short)f2b(vb[1]);
    o[6] = (short)f2b(vb[2]); o[7] = (short)f2b(vb[3]);
    *(s8v*)(dst + i * 8) = o;
  }
}

extern "C" void kernel_launch(void* const* d_in, const int* in_sizes, int n_in,
                              void* d_out, int out_size, void* d_ws, size_t ws_size,
                              hipStream_t stream) {
  const float* q    = (const float*)d_in[0];
  const float* k    = (const float*)d_in[1];
  const float* v    = (const float*)d_in[2];
  const float* mask = (const float*)d_in[3];
  const float* Wq   = (const float*)d_in[4];
  const float* bq   = (const float*)d_in[5];
  const float* Wk   = (const float*)d_in[6];
  const float* bk   = (const float*)d_in[7];
  const float* Wv   = (const float*)d_in[8];
  const float* bv   = (const float*)d_in[9];
  float* out = (float*)d_out;

  const size_t MB = 1ull << 20;
  if (ws_size < 134 * MB) return;
  char* ws = (char*)d_ws;
  unsigned short* qb  = (unsigned short*)(ws + 0 * MB);
  unsigned short* kb  = (unsigned short*)(ws + 16 * MB);
  unsigned short* vT  = (unsigned short*)(ws + 32 * MB);
  float*          sRw = (float*)(ws + 48 * MB);           // 32KB, own region
  unsigned short* Sb  = (unsigned short*)(ws + 80 * MB);  // aliases xq+xk (time-mux)
  unsigned short* xq  = (unsigned short*)(ws + 80 * MB);
  unsigned short* xk  = (unsigned short*)(ws + 96 * MB);
  unsigned short* xv  = (unsigned short*)(ws + 112 * MB);
  unsigned short* Wqb = (unsigned short*)(ws + 128 * MB);
  unsigned short* Wkb = (unsigned short*)(ws + 130 * MB);
  unsigned short* Wvb = (unsigned short*)(ws + 132 * MB);

  cvt7<<<2696, 256, 0, stream>>>(q, xq, k, xk, v, xv, Wq, Wqb, Wk, Wkb, Wv, Wvb,
                                 sRw);

  // QKV fused (one launch, 768 blocks): q-proj 256 (32x8 tiles), k-proj 256,
  // v-proj transposed 256 (vT: M=1024 -> 4 tm x 16 tn x 4 batches).
  Job jq = { xq, Wqb, (void*)qb, bq, nullptr, nullptr, 0, 0, 0, 0,
             1024, 1024, 1024, 0, 1024, 8, 256, 1.0f, 1 };
  Job jk = { xk, Wkb, (void*)kb, bk, nullptr, nullptr, 0, 0, 0, 0,
             1024, 1024, 1024, 0, 1024, 8, 256, 1.0f, 1 };
  Job jv = { Wvb, xv, (void*)vT, bv, nullptr, nullptr, 0, 2048L * 1024,
             1024L * 2048, 0, 1024, 1024, 2048, 0, 1024, 16, 64, 1.0f, 2 };
  gemmJ<2, 0><<<768, 512, 0, stream>>>(jq, jk, jv, 256, 512);

  // scores -> E = exp(qk/32 + mask), bf16, + row sums. 8x8x4 = 256 blocks.
  // Writes Sb over the (now dead) xq/xk region.
  Job js = { qb, kb, (void*)Sb, nullptr, mask, sRw,
             2048L * 1024, 2048L * 1024, 2048L * 2048, 2048L * 2048,
             1024, 1024, 2048, 2048, 1024, 8, 64, 0.03125f, 0 };
  gemmJ<4, 1><<<256, 512, 0, stream>>>(js, js, js, 256, 256);

  // PV: out = (E . vT^T) / s[row]; 8 tm x 8 tn x 4 = 256 blocks, K=2048.
  Job jp = { Sb, vT, (void*)out, nullptr, nullptr, sRw,
             2048L * 2048, 1024L * 2048, 2048L * 1024, 0,
             2048, 2048, 1024, 0, 2048, 8, 64, 1.0f, 0 };
  gemmJ<2, 2><<<256, 512, 0, stream>>>(jp, jp, jp, 256, 256);
}